// Round 5
// baseline (597.460 us; speedup 1.0000x reference)
//
#include <hip/hip_runtime.h>
#include <hip/hip_cooperative_groups.h>

namespace cg = cooperative_groups;

#define EMB 64
#define BKT_BITS 9                 // 512 rows per bucket
#define BKT_ROWS (1 << BKT_BITS)
#define BKT_CAP 4608               // fixed bucket capacity (mean 4096, +8 sigma)
#define MAX_BKT 512                // supports up to 262144 nodes
#define CO_EDGES 2048              // edges per coarse chunk (~586 chunks)

typedef float f32x4 __attribute__((ext_vector_type(4)));

// ---------------- shared device bodies (used by mega + fallback) ----------

__device__ __forceinline__ const float4* xrow(const float* xu,
                                              const float* xi,
                                              int nu, int col) {
    return (const float4*)((col < nu) ? (xu + (size_t)col * EMB)
                                      : (xi + (size_t)(col - nu) * EMB));
}

// Coarse scatter: bin a chunk by bucket in LDS, reserve per-bucket ranges
// with one global atomic per (chunk,bucket), scatter into fixed regions.
// Packs row's low 9 bits above the 18-bit col.
__device__ void coarse_body(const int* __restrict__ rows,
                            const int* __restrict__ cols,
                            const float* __restrict__ vals,
                            int* bcur, int2* __restrict__ es,
                            int n_edges, int nbkt,
                            int* lcnt, int* lbase,
                            int cstart, int cstride) {
    int tid = threadIdx.x;
    int nchunk = (n_edges + CO_EDGES - 1) / CO_EDGES;
    for (int c = cstart; c < nchunk; c += cstride) {
        for (int i = tid; i < nbkt; i += 512) lcnt[i] = 0;
        __syncthreads();
        int e0 = c * CO_EDGES;
        int e1 = min(e0 + CO_EDGES, n_edges);
        for (int e = e0 + tid; e < e1; e += 512)
            atomicAdd(&lcnt[rows[e] >> BKT_BITS], 1);
        __syncthreads();
        for (int i = tid; i < nbkt; i += 512) {
            int cc = lcnt[i];
            lbase[i] = cc ? atomicAdd(&bcur[i], cc) : 0;
        }
        __syncthreads();
        for (int e = e0 + tid; e < e1; e += 512) {
            int r = rows[e];
            int b = r >> BKT_BITS;
            int p = atomicAdd(&lbase[b], 1);
            if (p < BKT_CAP)   // statistically unreachable; guards corruption
                es[(size_t)b * BKT_CAP + p] =
                    make_int2(cols[e] | ((r & (BKT_ROWS - 1)) << 18),
                              __float_as_int(vals[e]));
        }
        __syncthreads();
    }
}

// Fine permute: stage bucket in LDS, count+scan per-row (emitting per-row
// [beg,end) coalesced), write back row-grouped in place (row bits stripped).
__device__ void fine_body(const int* bcur, int2* __restrict__ es,
                          int2* __restrict__ rbe, int n_nodes, int nbkt,
                          int2* stage, int* rcnt, int* rsc,
                          int bstart, int bstride) {
    int tid = threadIdx.x;          // blockDim.x == 512 == BKT_ROWS
    for (int b = bstart; b < nbkt; b += bstride) {
        int cnt = min(bcur[b], BKT_CAP);
        int base = b * BKT_CAP;
        rcnt[tid] = 0;
        __syncthreads();
        for (int j = tid; j < cnt; j += BKT_ROWS) {
            int2 e = es[base + j];
            stage[j] = e;
            atomicAdd(&rcnt[e.x >> 18], 1);
        }
        __syncthreads();
        int v = rcnt[tid];
        rsc[tid] = v;
        __syncthreads();
        for (int d = 1; d < BKT_ROWS; d <<= 1) {
            int t = (tid >= d) ? rsc[tid - d] : 0;
            __syncthreads();
            rsc[tid] += t;
            __syncthreads();
        }
        int excl = rsc[tid] - v;
        rcnt[tid] = excl;           // fill cursor
        int r = (b << BKT_BITS) + tid;
        if (r < n_nodes) rbe[r] = make_int2(base + excl, base + excl + v);
        __syncthreads();
        for (int j = tid; j < cnt; j += BKT_ROWS) {
            int2 e = stage[j];
            int p = atomicAdd(&rcnt[e.x >> 18], 1);
            es[base + p] = make_int2(e.x & 0x3FFFF, e.y);
        }
        __syncthreads();
    }
}

// Row-parallel SpMM, 16 lanes/row, 4-wide edge unroll, grid-stride.
// mode 0/1: y = a (PLAIN store -- y is the next layer's gather source and
//           must stay L2-resident; NT here cost +37 MB FETCH in round 4).
// mode 2:   out = 0.25*(x0[o] + y1[o] + y2[o] + a), NT store (never re-read).
__device__ void spmm_body(const int2* __restrict__ rbe,
                          const int2* __restrict__ es,
                          const float* xu, const float* xi, int nu,
                          float4* y, const float4* y1, const float4* y2,
                          const float* __restrict__ x0u,
                          const float* __restrict__ x0i,
                          int n_nodes, int mode, int gid0, int gstride) {
    int lanes = n_nodes * 16;
    for (int gid = gid0; gid < lanes; gid += gstride) {
        int r = gid >> 4;
        int q = gid & 15;
        int2 be = rbe[r];
        int beg = be.x;
        int end = be.y;
        float4 a = make_float4(0.f, 0.f, 0.f, 0.f);
        int j = beg;
        for (; j + 4 <= end; j += 4) {
            int2 e0 = es[j];
            int2 e1 = es[j + 1];
            int2 e2 = es[j + 2];
            int2 e3 = es[j + 3];
            float4 x0 = xrow(xu, xi, nu, e0.x)[q];
            float4 x1 = xrow(xu, xi, nu, e1.x)[q];
            float4 x2 = xrow(xu, xi, nu, e2.x)[q];
            float4 x3 = xrow(xu, xi, nu, e3.x)[q];
            float v0 = __int_as_float(e0.y);
            float v1 = __int_as_float(e1.y);
            float v2 = __int_as_float(e2.y);
            float v3 = __int_as_float(e3.y);
            a.x += v0 * x0.x; a.y += v0 * x0.y; a.z += v0 * x0.z; a.w += v0 * x0.w;
            a.x += v1 * x1.x; a.y += v1 * x1.y; a.z += v1 * x1.z; a.w += v1 * x1.w;
            a.x += v2 * x2.x; a.y += v2 * x2.y; a.z += v2 * x2.z; a.w += v2 * x2.w;
            a.x += v3 * x3.x; a.y += v3 * x3.y; a.z += v3 * x3.z; a.w += v3 * x3.w;
        }
        if (j + 2 <= end) {
            int2 e0 = es[j];
            int2 e1 = es[j + 1];
            float4 x0 = xrow(xu, xi, nu, e0.x)[q];
            float4 x1 = xrow(xu, xi, nu, e1.x)[q];
            float v0 = __int_as_float(e0.y);
            float v1 = __int_as_float(e1.y);
            a.x += v0 * x0.x; a.y += v0 * x0.y; a.z += v0 * x0.z; a.w += v0 * x0.w;
            a.x += v1 * x1.x; a.y += v1 * x1.y; a.z += v1 * x1.z; a.w += v1 * x1.w;
            j += 2;
        }
        if (j < end) {
            int2 e0 = es[j];
            float4 x0 = xrow(xu, xi, nu, e0.x)[q];
            float v0 = __int_as_float(e0.y);
            a.x += v0 * x0.x; a.y += v0 * x0.y; a.z += v0 * x0.z; a.w += v0 * x0.w;
        }
        size_t o = (size_t)r * (EMB / 4) + q;
        if (mode < 2) {
            y[o] = a;
        } else {
            const float4* b0 = (r < nu)
                ? ((const float4*)x0u + (size_t)r * (EMB / 4))
                : ((const float4*)x0i + (size_t)(r - nu) * (EMB / 4));
            float4 f0 = b0[q];
            float4 a1 = y1[o];
            float4 a2 = y2[o];
            float4 ac;
            ac.x = 0.25f * (f0.x + a1.x + a2.x + a.x);
            ac.y = 0.25f * (f0.y + a1.y + a2.y + a.y);
            ac.z = 0.25f * (f0.z + a1.z + a2.z + a.z);
            ac.w = 0.25f * (f0.w + a1.w + a2.w + a.w);
            __builtin_nontemporal_store(*(const f32x4*)&ac, (f32x4*)&y[o]);
        }
    }
}

// ---------------- single cooperative mega-kernel --------------------------
// Phases: zero cursors -> coarse -> fine -> spmm L1 -> L2 -> L3, separated
// by grid.sync(). Kills ~5 dispatch overheads (~13 us each, measured
// R3->R4: removing 9 us of kernel work dropped 31 us of wall).
__global__ __launch_bounds__(512, 6) void mega(
        const int* __restrict__ rows, const int* __restrict__ cols,
        const float* __restrict__ vals,
        int* bcur, int2* __restrict__ es, int2* __restrict__ rbe,
        const float* __restrict__ ue, const float* __restrict__ ie,
        float* y2buf, float* out,
        int nu, int n_nodes, int n_edges, int nbkt) {
    cg::grid_group grid = cg::this_grid();
    __shared__ int2 stage[BKT_CAP];   // 36 KB (aliased as lcnt/lbase in P1)
    __shared__ int rcnt[BKT_ROWS];    //  2 KB
    __shared__ int rsc[BKT_ROWS];     //  2 KB   -> 40 KB total, 3 blocks/CU
    int gid0 = blockIdx.x * blockDim.x + threadIdx.x;
    int gstride = gridDim.x * blockDim.x;

    // P0: zero bucket cursors
    for (int i = gid0; i < nbkt; i += gstride) bcur[i] = 0;
    grid.sync();

    // P1: coarse scatter
    coarse_body(rows, cols, vals, bcur, es, n_edges, nbkt,
                (int*)stage, (int*)stage + MAX_BKT, blockIdx.x, gridDim.x);
    grid.sync();

    // P2: fine permute + rbe
    fine_body(bcur, es, rbe, n_nodes, nbkt, stage, rcnt, rsc,
              blockIdx.x, gridDim.x);
    grid.sync();

    // P3: layer 1, x = [ue;ie] -> y1 = out
    spmm_body(rbe, es, ue, ie, nu, (float4*)out,
              nullptr, nullptr, nullptr, nullptr, n_nodes, 0, gid0, gstride);
    grid.sync();

    // P4: layer 2, x = y1 -> y2buf
    spmm_body(rbe, es, out, out + (size_t)nu * EMB, nu, (float4*)y2buf,
              nullptr, nullptr, nullptr, nullptr, n_nodes, 1, gid0, gstride);
    grid.sync();

    // P5: layer 3, x = y2buf; out = 0.25*(x0 + y1 + y2 + a)
    spmm_body(rbe, es, y2buf, y2buf + (size_t)nu * EMB, nu, (float4*)out,
              (const float4*)out, (const float4*)y2buf, ue, ie,
              n_nodes, 2, gid0, gstride);
}

// ---------------- fallback multi-dispatch kernels -------------------------

__global__ __launch_bounds__(512) void k_coarse(
        const int* __restrict__ rows, const int* __restrict__ cols,
        const float* __restrict__ vals, int* bcur, int2* __restrict__ es,
        int n_edges, int nbkt) {
    __shared__ int lcnt[MAX_BKT];
    __shared__ int lbase[MAX_BKT];
    coarse_body(rows, cols, vals, bcur, es, n_edges, nbkt,
                lcnt, lbase, blockIdx.x, gridDim.x);
}

__global__ __launch_bounds__(512) void k_fine(
        const int* bcur, int2* __restrict__ es, int2* __restrict__ rbe,
        int n_nodes, int nbkt) {
    __shared__ int2 stage[BKT_CAP];
    __shared__ int rcnt[BKT_ROWS];
    __shared__ int rsc[BKT_ROWS];
    fine_body(bcur, es, rbe, n_nodes, nbkt, stage, rcnt, rsc,
              blockIdx.x, gridDim.x);
}

__global__ __launch_bounds__(512) void k_spmm(
        const int2* __restrict__ rbe, const int2* __restrict__ es,
        const float* xu, const float* xi, int nu,
        float4* y, const float4* y1, const float4* y2,
        const float* __restrict__ x0u, const float* __restrict__ x0i,
        int n_nodes, int mode) {
    spmm_body(rbe, es, xu, xi, nu, y, y1, y2, x0u, x0i, n_nodes, mode,
              blockIdx.x * blockDim.x + threadIdx.x,
              gridDim.x * blockDim.x);
}

extern "C" void kernel_launch(void* const* d_in, const int* in_sizes, int n_in,
                              void* d_out, int out_size, void* d_ws, size_t ws_size,
                              hipStream_t stream) {
    const float* ue   = (const float*)d_in[0];
    const float* ie   = (const float*)d_in[1];
    const int*   rows = (const int*)d_in[2];
    const int*   cols = (const int*)d_in[3];
    const float* vals = (const float*)d_in[4];
    float* out = (float*)d_out;

    const int num_users = in_sizes[0] / EMB;
    const int num_items = in_sizes[1] / EMB;
    const int n_nodes   = num_users + num_items;
    const int n_edges   = in_sizes[2];
    const int nbkt      = (n_nodes + BKT_ROWS - 1) >> BKT_BITS;   // 293

    // Workspace (~50.5 MB): y2buf | es (padded, nbkt*BKT_CAP) | rbe | bcur
    const size_t buf_elems = (size_t)n_nodes * EMB;
    float* y2buf = (float*)d_ws;
    int2*  es    = (int2*)(y2buf + buf_elems);
    int2*  rbe   = es + (size_t)nbkt * BKT_CAP;
    int*   bcur  = (int*)(rbe + n_nodes);

    // Co-resident grid size for the cooperative launch (cached).
    static int grid_blocks = 0;
    if (grid_blocks == 0) {
        int occ = 0, cus = 0, dev = 0;
        hipGetDevice(&dev);
        hipOccupancyMaxActiveBlocksPerMultiprocessor(&occ, mega, 512, 0);
        hipDeviceGetAttribute(&cus, hipDeviceAttributeMultiprocessorCount, dev);
        if (occ < 1) occ = 1;
        if (occ > 4) occ = 4;
        if (cus < 1) cus = 256;
        grid_blocks = occ * cus;   // expect 3 * 256 = 768
    }

    int nu = num_users, nn = n_nodes, ne = n_edges, nb = nbkt;
    void* args[] = { (void*)&rows, (void*)&cols, (void*)&vals,
                     (void*)&bcur, (void*)&es, (void*)&rbe,
                     (void*)&ue, (void*)&ie, (void*)&y2buf, (void*)&out,
                     (void*)&nu, (void*)&nn, (void*)&ne, (void*)&nb };
    hipError_t err = hipLaunchCooperativeKernel(
        mega, dim3(grid_blocks), dim3(512), args, 0, stream);

    if (err != hipSuccess) {
        // Fallback: identical device code, classic dispatches.
        (void)hipGetLastError();
        hipMemsetAsync(bcur, 0, (size_t)nbkt * sizeof(int), stream);
        int nchunk = (n_edges + CO_EDGES - 1) / CO_EDGES;
        k_coarse<<<nchunk, 512, 0, stream>>>(rows, cols, vals, bcur, es,
                                             n_edges, nbkt);
        k_fine<<<nbkt, 512, 0, stream>>>(bcur, es, rbe, n_nodes, nbkt);
        int blocks = (n_nodes * 16 + 511) / 512;
        k_spmm<<<blocks, 512, 0, stream>>>(
            rbe, es, ue, ie, num_users, (float4*)out,
            nullptr, nullptr, nullptr, nullptr, n_nodes, 0);
        k_spmm<<<blocks, 512, 0, stream>>>(
            rbe, es, (const float*)out,
            (const float*)out + (size_t)num_users * EMB, num_users,
            (float4*)y2buf, nullptr, nullptr, nullptr, nullptr, n_nodes, 1);
        k_spmm<<<blocks, 512, 0, stream>>>(
            rbe, es, y2buf, y2buf + (size_t)num_users * EMB, num_users,
            (float4*)out, (const float4*)out, (const float4*)y2buf,
            ue, ie, n_nodes, 2);
    }
}

// Round 6
// 285.653 us; speedup vs baseline: 2.0916x; 2.0916x over previous
//
#include <hip/hip_runtime.h>
#include <hip/hip_cooperative_groups.h>

namespace cg = cooperative_groups;

#define EMB 64
#define BKT_BITS 9                 // 512 rows per bucket
#define BKT_ROWS (1 << BKT_BITS)
#define BKT_CAP 4608               // fixed bucket capacity (mean 4096, +8 sigma)
#define MAX_BKT 512                // supports up to 262144 nodes
#define CO_EDGES 2048              // edges per coarse chunk (~586 chunks)

typedef float f32x4 __attribute__((ext_vector_type(4)));

// ---------------- shared device bodies (used by mega + fallback) ----------

__device__ __forceinline__ const float4* xrow(const float* xu,
                                              const float* xi,
                                              int nu, int col) {
    return (const float4*)((col < nu) ? (xu + (size_t)col * EMB)
                                      : (xi + (size_t)(col - nu) * EMB));
}

// Coarse scatter: bin a chunk by bucket in LDS, reserve per-bucket ranges
// with one global atomic per (chunk,bucket), scatter into fixed regions of
// es_raw. Packs row's low 9 bits above the 18-bit col.
__device__ void coarse_body(const int* __restrict__ rows,
                            const int* __restrict__ cols,
                            const float* __restrict__ vals,
                            int* bcur, int2* __restrict__ es_raw,
                            int n_edges, int nbkt,
                            int* lcnt, int* lbase,
                            int cstart, int cstride) {
    int tid = threadIdx.x;           // blockDim.x == 512
    int nchunk = (n_edges + CO_EDGES - 1) / CO_EDGES;
    for (int c = cstart; c < nchunk; c += cstride) {
        for (int i = tid; i < nbkt; i += 512) lcnt[i] = 0;
        __syncthreads();
        int e0 = c * CO_EDGES;
        int e1 = min(e0 + CO_EDGES, n_edges);
        for (int e = e0 + tid; e < e1; e += 512)
            atomicAdd(&lcnt[rows[e] >> BKT_BITS], 1);
        __syncthreads();
        for (int i = tid; i < nbkt; i += 512) {
            int cc = lcnt[i];
            lbase[i] = cc ? atomicAdd(&bcur[i], cc) : 0;
        }
        __syncthreads();
        for (int e = e0 + tid; e < e1; e += 512) {
            int r = rows[e];
            int b = r >> BKT_BITS;
            int p = atomicAdd(&lbase[b], 1);
            if (p < BKT_CAP)   // statistically unreachable; guards corruption
                es_raw[(size_t)b * BKT_CAP + p] =
                    make_int2(cols[e] | ((r & (BKT_ROWS - 1)) << 18),
                              __float_as_int(vals[e]));
        }
        __syncthreads();
    }
}

// Fine permute, NO LDS staging (round-5 lesson: the 36 KB stage capped
// residency). Two passes over es_raw (L2-resident, bucket region ~36 KB):
// count per-row -> LDS scan (emits per-row [beg,end) coalesced) -> permute
// es_raw into row-grouped es (out-of-place; row bits stripped). LDS: 4 KB.
__device__ void fine_body(const int* bcur,
                          const int2* __restrict__ es_raw,
                          int2* __restrict__ es,
                          int2* __restrict__ rbe, int n_nodes, int nbkt,
                          int* rcnt, int* rsc,
                          int bstart, int bstride) {
    int tid = threadIdx.x;          // blockDim.x == 512 == BKT_ROWS
    for (int b = bstart; b < nbkt; b += bstride) {
        int cnt = min(bcur[b], BKT_CAP);
        int base = b * BKT_CAP;
        rcnt[tid] = 0;
        __syncthreads();
        for (int j = tid; j < cnt; j += BKT_ROWS)
            atomicAdd(&rcnt[es_raw[base + j].x >> 18], 1);
        __syncthreads();
        int v = rcnt[tid];
        rsc[tid] = v;
        __syncthreads();
        for (int d = 1; d < BKT_ROWS; d <<= 1) {
            int t = (tid >= d) ? rsc[tid - d] : 0;
            __syncthreads();
            rsc[tid] += t;
            __syncthreads();
        }
        int excl = rsc[tid] - v;
        rcnt[tid] = excl;           // fill cursor
        int r = (b << BKT_BITS) + tid;
        if (r < n_nodes) rbe[r] = make_int2(base + excl, base + excl + v);
        __syncthreads();
        for (int j = tid; j < cnt; j += BKT_ROWS) {
            int2 e = es_raw[base + j];
            int p = atomicAdd(&rcnt[e.x >> 18], 1);
            es[base + p] = make_int2(e.x & 0x3FFFF, e.y);
        }
        __syncthreads();
    }
}

// Row-parallel SpMM, 16 lanes/row, 4-wide edge unroll, grid-stride.
// mode 0/1: y = a, PLAIN store (y is next layer's gather source; NT here
//           cost +37 MB FETCH in round 4).
// mode 2:   out = 0.25*(x0[o] + y1[o] + y2[o] + a), NT store (never re-read).
__device__ void spmm_body(const int2* __restrict__ rbe,
                          const int2* __restrict__ es,
                          const float* xu, const float* xi, int nu,
                          float4* y, const float4* y1, const float4* y2,
                          const float* __restrict__ x0u,
                          const float* __restrict__ x0i,
                          int n_nodes, int mode, int gid0, int gstride) {
    int lanes = n_nodes * 16;
    for (int gid = gid0; gid < lanes; gid += gstride) {
        int r = gid >> 4;
        int q = gid & 15;
        int2 be = rbe[r];
        int beg = be.x;
        int end = be.y;
        float4 a = make_float4(0.f, 0.f, 0.f, 0.f);
        int j = beg;
        for (; j + 4 <= end; j += 4) {
            int2 e0 = es[j];
            int2 e1 = es[j + 1];
            int2 e2 = es[j + 2];
            int2 e3 = es[j + 3];
            float4 x0 = xrow(xu, xi, nu, e0.x)[q];
            float4 x1 = xrow(xu, xi, nu, e1.x)[q];
            float4 x2 = xrow(xu, xi, nu, e2.x)[q];
            float4 x3 = xrow(xu, xi, nu, e3.x)[q];
            float v0 = __int_as_float(e0.y);
            float v1 = __int_as_float(e1.y);
            float v2 = __int_as_float(e2.y);
            float v3 = __int_as_float(e3.y);
            a.x += v0 * x0.x; a.y += v0 * x0.y; a.z += v0 * x0.z; a.w += v0 * x0.w;
            a.x += v1 * x1.x; a.y += v1 * x1.y; a.z += v1 * x1.z; a.w += v1 * x1.w;
            a.x += v2 * x2.x; a.y += v2 * x2.y; a.z += v2 * x2.z; a.w += v2 * x2.w;
            a.x += v3 * x3.x; a.y += v3 * x3.y; a.z += v3 * x3.z; a.w += v3 * x3.w;
        }
        if (j + 2 <= end) {
            int2 e0 = es[j];
            int2 e1 = es[j + 1];
            float4 x0 = xrow(xu, xi, nu, e0.x)[q];
            float4 x1 = xrow(xu, xi, nu, e1.x)[q];
            float v0 = __int_as_float(e0.y);
            float v1 = __int_as_float(e1.y);
            a.x += v0 * x0.x; a.y += v0 * x0.y; a.z += v0 * x0.z; a.w += v0 * x0.w;
            a.x += v1 * x1.x; a.y += v1 * x1.y; a.z += v1 * x1.z; a.w += v1 * x1.w;
            j += 2;
        }
        if (j < end) {
            int2 e0 = es[j];
            float4 x0 = xrow(xu, xi, nu, e0.x)[q];
            float v0 = __int_as_float(e0.y);
            a.x += v0 * x0.x; a.y += v0 * x0.y; a.z += v0 * x0.z; a.w += v0 * x0.w;
        }
        size_t o = (size_t)r * (EMB / 4) + q;
        if (mode < 2) {
            y[o] = a;
        } else {
            const float4* b0 = (r < nu)
                ? ((const float4*)x0u + (size_t)r * (EMB / 4))
                : ((const float4*)x0i + (size_t)(r - nu) * (EMB / 4));
            float4 f0 = b0[q];
            float4 a1 = y1[o];
            float4 a2 = y2[o];
            float4 ac;
            ac.x = 0.25f * (f0.x + a1.x + a2.x + a.x);
            ac.y = 0.25f * (f0.y + a1.y + a2.y + a.y);
            ac.z = 0.25f * (f0.z + a1.z + a2.z + a.z);
            ac.w = 0.25f * (f0.w + a1.w + a2.w + a.w);
            __builtin_nontemporal_store(*(const f32x4*)&ac, (f32x4*)&y[o]);
        }
    }
}

// ---------------- single cooperative mega-kernel --------------------------
// Round-5 fixes: NO min-waves in launch_bounds (the (512,6) cap forced
// VGPR=24 -> spmm inner-loop spilled to scratch, +28 MB writes, 4x slower),
// NO 36 KB LDS stage (capped residency at 3-4 blocks/CU). LDS now 8 KB.
__global__ __launch_bounds__(512) void mega(
        const int* __restrict__ rows, const int* __restrict__ cols,
        const float* __restrict__ vals,
        int* bcur, int2* __restrict__ es_raw, int2* __restrict__ es,
        int2* __restrict__ rbe,
        const float* __restrict__ ue, const float* __restrict__ ie,
        float* y2buf, float* out,
        int nu, int n_nodes, int n_edges, int nbkt) {
    cg::grid_group grid = cg::this_grid();
    __shared__ int lcnt[MAX_BKT];     // 2 KB (coarse)
    __shared__ int lbase[MAX_BKT];    // 2 KB (coarse)
    __shared__ int rcnt[BKT_ROWS];    // 2 KB (fine)
    __shared__ int rsc[BKT_ROWS];     // 2 KB (fine)
    int gid0 = blockIdx.x * blockDim.x + threadIdx.x;
    int gstride = gridDim.x * blockDim.x;

    // P0: zero bucket cursors
    for (int i = gid0; i < nbkt; i += gstride) bcur[i] = 0;
    grid.sync();

    // P1: coarse scatter -> es_raw
    coarse_body(rows, cols, vals, bcur, es_raw, n_edges, nbkt,
                lcnt, lbase, blockIdx.x, gridDim.x);
    grid.sync();

    // P2: fine permute es_raw -> es, emit rbe
    fine_body(bcur, es_raw, es, rbe, n_nodes, nbkt, rcnt, rsc,
              blockIdx.x, gridDim.x);
    grid.sync();

    // P3: layer 1, x = [ue;ie] -> y1 = out
    spmm_body(rbe, es, ue, ie, nu, (float4*)out,
              nullptr, nullptr, nullptr, nullptr, n_nodes, 0, gid0, gstride);
    grid.sync();

    // P4: layer 2, x = y1 -> y2buf
    spmm_body(rbe, es, out, out + (size_t)nu * EMB, nu, (float4*)y2buf,
              nullptr, nullptr, nullptr, nullptr, n_nodes, 1, gid0, gstride);
    grid.sync();

    // P5: layer 3, x = y2buf; out = 0.25*(x0 + y1 + y2 + a)
    spmm_body(rbe, es, y2buf, y2buf + (size_t)nu * EMB, nu, (float4*)out,
              (const float4*)out, (const float4*)y2buf, ue, ie,
              n_nodes, 2, gid0, gstride);
}

// ---------------- fallback multi-dispatch kernels -------------------------

__global__ __launch_bounds__(512) void k_coarse(
        const int* __restrict__ rows, const int* __restrict__ cols,
        const float* __restrict__ vals, int* bcur, int2* __restrict__ es_raw,
        int n_edges, int nbkt) {
    __shared__ int lcnt[MAX_BKT];
    __shared__ int lbase[MAX_BKT];
    coarse_body(rows, cols, vals, bcur, es_raw, n_edges, nbkt,
                lcnt, lbase, blockIdx.x, gridDim.x);
}

__global__ __launch_bounds__(512) void k_fine(
        const int* bcur, const int2* __restrict__ es_raw,
        int2* __restrict__ es, int2* __restrict__ rbe,
        int n_nodes, int nbkt) {
    __shared__ int rcnt[BKT_ROWS];
    __shared__ int rsc[BKT_ROWS];
    fine_body(bcur, es_raw, es, rbe, n_nodes, nbkt, rcnt, rsc,
              blockIdx.x, gridDim.x);
}

__global__ __launch_bounds__(256) void k_spmm(
        const int2* __restrict__ rbe, const int2* __restrict__ es,
        const float* xu, const float* xi, int nu,
        float4* y, const float4* y1, const float4* y2,
        const float* __restrict__ x0u, const float* __restrict__ x0i,
        int n_nodes, int mode) {
    spmm_body(rbe, es, xu, xi, nu, y, y1, y2, x0u, x0i, n_nodes, mode,
              blockIdx.x * blockDim.x + threadIdx.x,
              gridDim.x * blockDim.x);
}

extern "C" void kernel_launch(void* const* d_in, const int* in_sizes, int n_in,
                              void* d_out, int out_size, void* d_ws, size_t ws_size,
                              hipStream_t stream) {
    const float* ue   = (const float*)d_in[0];
    const float* ie   = (const float*)d_in[1];
    const int*   rows = (const int*)d_in[2];
    const int*   cols = (const int*)d_in[3];
    const float* vals = (const float*)d_in[4];
    float* out = (float*)d_out;

    const int num_users = in_sizes[0] / EMB;
    const int num_items = in_sizes[1] / EMB;
    const int n_nodes   = num_users + num_items;
    const int n_edges   = in_sizes[2];
    const int nbkt      = (n_nodes + BKT_ROWS - 1) >> BKT_BITS;   // 293

    // Workspace (~61.3 MB):
    //  y2buf (38.4) | es (10.8) | es_raw (10.8) | rbe (1.2) | bcur (1.2 KB)
    const size_t buf_elems = (size_t)n_nodes * EMB;
    float* y2buf  = (float*)d_ws;
    int2*  es     = (int2*)(y2buf + buf_elems);
    int2*  es_raw = es + (size_t)nbkt * BKT_CAP;
    int2*  rbe    = es_raw + (size_t)nbkt * BKT_CAP;
    int*   bcur   = (int*)(rbe + n_nodes);

    // Co-resident grid for cooperative launch. Require occ >= 3 blocks/CU
    // (24+ waves/CU, the level that sustained 3.8 TB/s in rounds 3-4);
    // otherwise use the classic multi-dispatch path.
    int occ = 0, cus = 0, dev = 0;
    hipGetDevice(&dev);
    hipOccupancyMaxActiveBlocksPerMultiprocessor(&occ, mega, 512, 0);
    hipDeviceGetAttribute(&cus, hipDeviceAttributeMultiprocessorCount, dev);
    if (cus < 1) cus = 256;
    if (occ > 4) occ = 4;

    bool done = false;
    if (occ >= 3) {
        int grid_blocks = occ * cus;
        int nu = num_users, nn = n_nodes, ne = n_edges, nb = nbkt;
        void* args[] = { (void*)&rows, (void*)&cols, (void*)&vals,
                         (void*)&bcur, (void*)&es_raw, (void*)&es,
                         (void*)&rbe, (void*)&ue, (void*)&ie,
                         (void*)&y2buf, (void*)&out,
                         (void*)&nu, (void*)&nn, (void*)&ne, (void*)&nb };
        hipError_t err = hipLaunchCooperativeKernel(
            mega, dim3(grid_blocks), dim3(512), args, 0, stream);
        done = (err == hipSuccess);
        if (!done) (void)hipGetLastError();
    }

    if (!done) {
        // Fallback: identical device code, classic dispatches (round-4
        // structure with the NT-store fix).
        hipMemsetAsync(bcur, 0, (size_t)nbkt * sizeof(int), stream);
        int nchunk = (n_edges + CO_EDGES - 1) / CO_EDGES;
        k_coarse<<<nchunk, 512, 0, stream>>>(rows, cols, vals, bcur, es_raw,
                                             n_edges, nbkt);
        k_fine<<<nbkt, 512, 0, stream>>>(bcur, es_raw, es, rbe,
                                         n_nodes, nbkt);
        int blocks = (n_nodes * 16 + 255) / 256;
        k_spmm<<<blocks, 256, 0, stream>>>(
            rbe, es, ue, ie, num_users, (float4*)out,
            nullptr, nullptr, nullptr, nullptr, n_nodes, 0);
        k_spmm<<<blocks, 256, 0, stream>>>(
            rbe, es, (const float*)out,
            (const float*)out + (size_t)num_users * EMB, num_users,
            (float4*)y2buf, nullptr, nullptr, nullptr, nullptr, n_nodes, 1);
        k_spmm<<<blocks, 256, 0, stream>>>(
            rbe, es, y2buf, y2buf + (size_t)num_users * EMB, num_users,
            (float4*)out, (const float4*)out, (const float4*)y2buf,
            ue, ie, n_nodes, 2);
    }
}